// Round 7
// baseline (762.083 us; speedup 1.0000x reference)
//
#include <hip/hip_runtime.h>

#define FF 512
#define LL 12288
#define NJC 1556   // XB chunk count (zero pad tail covers prefetch overrun; max jc ~1538)
#define NR 128     // XB rows = 16 shifts x 8 batches (only s<8 used by conv_main)

typedef _Float16 half8  __attribute__((ext_vector_type(8)));
typedef float    f32x16 __attribute__((ext_vector_type(16)));

// ---------------- Prologue 1: kernel fp32 -> f16, 32x32x16 A-fragment tiled
// At chunk (ft,kc,lane): elem_j = kernel[ft*32 + (lane&31)][kc*16 + (lane>>5)*8 + j]
// ft in [0,16), kc in [0,768)
__global__ __launch_bounds__(256) void build_At(const float* __restrict__ kern,
                                                _Float16* __restrict__ At) {
    int tid  = blockIdx.x * 256 + threadIdx.x;      // 786432 = 16*768*64
    int lane = tid & 63;
    int rest = tid >> 6;                            // ft*768 + kc
    int kc   = rest % 768;
    int ft   = rest / 768;
    int f    = ft * 32 + (lane & 31);
    int d0   = kc * 16 + (lane >> 5) * 8;
    const float* src = kern + (size_t)f * LL + d0;
    half8 v;
#pragma unroll
    for (int i = 0; i < 8; ++i) v[i] = (_Float16)src[i];
    ((half8*)At)[tid] = v;
}

// ---------------- Prologue 2: B chunk-major layout -------------------------
// XB[jc][r] (16B chunks): r = s*8 + b, s in [0,16). elem_i = x_b[LL-1-(8jc+i)-s]
// (zero when index < 0 -> causal mask, incl. the whole jc >= 1536 pad tail).
__global__ __launch_bounds__(256) void build_XB(const int* __restrict__ ex,
                                                _Float16* __restrict__ XB) {
    int tid = blockIdx.x * 256 + threadIdx.x;       // 199168 = NJC*NR
    if (tid >= NJC * NR) return;
    int r  = tid & 127;
    int jc = tid >> 7;
    int s  = r >> 3, b = r & 7;
    int j0 = jc * 8;
    half8 v;
#pragma unroll
    for (int i = 0; i < 8; ++i) {
        int idx = LL - 1 - (j0 + i) - s;
        float x = 0.f;
        if (idx >= 0) x = (float)ex[b * LL + idx] * 0.5f - 1.0f;
        v[i] = (_Float16)x;
    }
    ((half8*)XB)[tid] = v;
}

// ---------------- Prologue 3: out = dense_b broadcast ----------------------
__global__ __launch_bounds__(256) void init_out(const float* __restrict__ db,
                                                float* __restrict__ out) {
    int tid = blockIdx.x * 256 + threadIdx.x;       // 393216
    out[tid] = db[tid & 3];
}

// ---------------- Main: barrier-free, LDS-free, register-direct A+B --------
// Block 128f x 256cols (8b x 32n), 4 waves, wave tile 128x64 = 4(m)x2(n)
// 32x32x16 tiles -> acc 4x2x16 = 128 AGPR. NO LDS, NO __syncthreads: per
// k16-step each wave loads 4 A chunks (1KB, block-shared addresses -> L1
// reuse) + 2 B chunks, rotating 1-step prefetch. Compiler emits fine-grained
// vmcnt(N) with loads in flight across steps (AITER-style, no vmcnt(0)).
// Wave cols: tile ti: n = n0 + (wid*2+ti)*4 + nh, b = bb  (nh = (lane>>3)&3).
__global__ __launch_bounds__(256, 2) void conv_main(const _Float16* __restrict__ At,
                                                    const _Float16* __restrict__ XB,
                                                    const float* __restrict__ bias,
                                                    const float* __restrict__ dw,
                                                    float* __restrict__ out) {
    int bx    = blockIdx.x;               // 1536 blocks
    int slot  = bx & 7;                   // XCD pin: f_blk per XCD pair
    int f_blk = slot >> 1;                // [0,4)
    int n_blk = 383 - ((bx >> 3) * 2 + (slot & 1));   // largest K first
    int n0 = n_blk << 5;
    int T  = 2 * (n_blk + 1);             // k16 steps (exact K, no round-up)

    int tid  = threadIdx.x;
    int lane = tid & 63;
    int wid  = tid >> 6;
    int kh   = lane >> 5;                 // k-half within fragment
    int bb   = lane & 7;
    int nh   = (lane >> 3) & 3;

    // A streams: 4 chunks per k16 (one per 32-row m-tile); consecutive k16
    // are 64 half8 apart.
    const half8* Ag = (const half8*)At;
    const half8* pAm[4];
#pragma unroll
    for (int mt = 0; mt < 4; ++mt)
        pAm[mt] = Ag + ((size_t)(f_blk * 4 + mt) * 768) * 64 + lane;

    // B streams: 2 per wave (one per n-tile); consecutive k16 are 256 apart.
    const half8* Bg = (const half8*)XB;
    const half8* pB[2];
#pragma unroll
    for (int ti = 0; ti < 2; ++ti) {
        int n_base = n0 + (wid * 2 + ti) * 4;
        int Qt = LL - 1 - n_base - nh;
        int s  = Qt & 7;
        int jc0 = Qt >> 3;                // uniform across nh (base mod 8 >= 3)
        pB[ti] = Bg + (size_t)(jc0 + kh) * 128 + s * 8 + bb;
    }

    f32x16 acc[4][2];
#pragma unroll
    for (int mt = 0; mt < 4; ++mt)
#pragma unroll
        for (int ti = 0; ti < 2; ++ti)
#pragma unroll
            for (int r = 0; r < 16; ++r) acc[mt][ti][r] = 0.f;

    half8 a[2][4], b[2][2];
    // prologue: load k16 step 0 into parity 0
#pragma unroll
    for (int mt = 0; mt < 4; ++mt) a[0][mt] = pAm[mt][0];
#pragma unroll
    for (int ti = 0; ti < 2; ++ti) b[0][ti] = pB[ti][0];

    // T is always even; process 2 k16 steps per iteration.
    // Prefetch overrun at kk+2 == T reads <=1 chunk past the logical end:
    // A lands inside At/XB allocation (harmless), B lands in XB zero pad.
    for (int kk = 0; kk < T; kk += 2) {
        size_t o1 = (size_t)(kk + 1);
#pragma unroll
        for (int mt = 0; mt < 4; ++mt) a[1][mt] = pAm[mt][o1 * 64];
#pragma unroll
        for (int ti = 0; ti < 2; ++ti) b[1][ti] = pB[ti][o1 * 256];
#pragma unroll
        for (int mt = 0; mt < 4; ++mt)
#pragma unroll
            for (int ti = 0; ti < 2; ++ti)
                acc[mt][ti] = __builtin_amdgcn_mfma_f32_32x32x16_f16(a[0][mt], b[0][ti], acc[mt][ti], 0, 0, 0);
        size_t o2 = (size_t)(kk + 2);
#pragma unroll
        for (int mt = 0; mt < 4; ++mt) a[0][mt] = pAm[mt][o2 * 64];
#pragma unroll
        for (int ti = 0; ti < 2; ++ti) b[0][ti] = pB[ti][o2 * 256];
#pragma unroll
        for (int mt = 0; mt < 4; ++mt)
#pragma unroll
            for (int ti = 0; ti < 2; ++ti)
                acc[mt][ti] = __builtin_amdgcn_mfma_f32_32x32x16_f16(a[1][mt], b[1][ti], acc[mt][ti], 0, 0, 0);
    }

    // Epilogue: bias + relu + dense over this block's 128 f rows.
    // C/D 32x32 layout: col = lane&31, row = (reg&3) + 8*(reg>>2) + 4*(lane>>5).
    float p[2][4] = {{0.f}};
#pragma unroll
    for (int mt = 0; mt < 4; ++mt) {
#pragma unroll
        for (int reg = 0; reg < 16; ++reg) {
            int row = (reg & 3) + 8 * (reg >> 2) + 4 * kh;
            int f   = f_blk * 128 + mt * 32 + row;
            float bs = bias[f];
            float4 w = *(const float4*)(dw + (size_t)f * 4);
#pragma unroll
            for (int ti = 0; ti < 2; ++ti) {
                float y = fmaxf(acc[mt][ti][reg] + bs, 0.f);
                p[ti][0] += y * w.x; p[ti][1] += y * w.y;
                p[ti][2] += y * w.z; p[ti][3] += y * w.w;
            }
        }
    }
    // combine the two k-halves (rows differ by 4): lane <-> lane^32
#pragma unroll
    for (int ti = 0; ti < 2; ++ti)
#pragma unroll
        for (int c = 0; c < 4; ++c) {
            float v = p[ti][c];
            v += __shfl_xor(v, 32, 64);
            p[ti][c] = v;
        }
    if (kh == 0) {
#pragma unroll
        for (int ti = 0; ti < 2; ++ti) {
            int n = n0 + (wid * 2 + ti) * 4 + nh;
            float* o = out + ((size_t)bb * LL + n) * 4;
#pragma unroll
            for (int c = 0; c < 4; ++c) atomicAdd(o + c, p[ti][c]);
        }
    }
}

extern "C" void kernel_launch(void* const* d_in, const int* in_sizes, int n_in,
                              void* d_out, int out_size, void* d_ws, size_t ws_size,
                              hipStream_t stream) {
    const int*   ex   = (const int*)d_in[0];
    const float* kern = (const float*)d_in[1];
    const float* bias = (const float*)d_in[2];
    const float* dw   = (const float*)d_in[3];
    const float* db   = (const float*)d_in[4];
    float* out = (float*)d_out;

    _Float16* At = (_Float16*)d_ws;                                   // 12.58 MB
    _Float16* XB = (_Float16*)((char*)d_ws + (size_t)FF * LL * 2);    // +3.19 MB

    hipLaunchKernelGGL(build_At, dim3(3072), dim3(256), 0, stream, kern, At);
    hipLaunchKernelGGL(build_XB, dim3(778),  dim3(256), 0, stream, ex, XB);
    hipLaunchKernelGGL(init_out, dim3(1536), dim3(256), 0, stream, db, out);
    hipLaunchKernelGGL(conv_main, dim3(1536), dim3(256), 0, stream, At, XB, bias, dw, out);
}

// Round 8
// 546.839 us; speedup vs baseline: 1.3936x; 1.3936x over previous
//
#include <hip/hip_runtime.h>

#define FF 512
#define LL 12288
#define NJC 1560   // XB chunk count (zero pad covers K-roundup + depth-2 prefetch; max jc = 1558)
#define NR 128     // XB rows = 16 shifts x 8 batches (only s<8 used by conv_main)

typedef _Float16 half8  __attribute__((ext_vector_type(8)));
typedef float    f32x16 __attribute__((ext_vector_type(16)));

// ---------------- Prologue 1: kernel fp32 -> f16, 32x32x16 A-fragment tiled
// At chunk (ft,kc,lane): elem_j = kernel[ft*32 + (lane&31)][kc*16 + (lane>>5)*8 + j]
// ft in [0,16), kc in [0,768)
__global__ __launch_bounds__(256) void build_At(const float* __restrict__ kern,
                                                _Float16* __restrict__ At) {
    int tid  = blockIdx.x * 256 + threadIdx.x;      // 786432 = 16*768*64
    int lane = tid & 63;
    int rest = tid >> 6;                            // ft*768 + kc
    int kc   = rest % 768;
    int ft   = rest / 768;
    int f    = ft * 32 + (lane & 31);
    int d0   = kc * 16 + (lane >> 5) * 8;
    const float* src = kern + (size_t)f * LL + d0;
    half8 v;
#pragma unroll
    for (int i = 0; i < 8; ++i) v[i] = (_Float16)src[i];
    ((half8*)At)[tid] = v;
}

// ---------------- Prologue 2: B chunk-major layout -------------------------
// XB[jc][r] (16B chunks): r = s*8 + b, s in [0,16). elem_i = x_b[LL-1-(8jc+i)-s]
// (zero when index < 0 -> causal mask, incl. the whole jc >= 1536 pad tail).
__global__ __launch_bounds__(256) void build_XB(const int* __restrict__ ex,
                                                _Float16* __restrict__ XB) {
    int tid = blockIdx.x * 256 + threadIdx.x;       // 199680 = NJC*NR
    int r  = tid & 127;
    int jc = tid >> 7;
    int s  = r >> 3, b = r & 7;
    int j0 = jc * 8;
    half8 v;
#pragma unroll
    for (int i = 0; i < 8; ++i) {
        int idx = LL - 1 - (j0 + i) - s;
        float x = 0.f;
        if (idx >= 0) x = (float)ex[b * LL + idx] * 0.5f - 1.0f;
        v[i] = (_Float16)x;
    }
    ((half8*)XB)[tid] = v;
}

// ---------------- Prologue 3: out = dense_b broadcast ----------------------
__global__ __launch_bounds__(256) void init_out(const float* __restrict__ db,
                                                float* __restrict__ out) {
    int tid = blockIdx.x * 256 + threadIdx.x;       // 393216
    out[tid] = db[tid & 3];
}

__device__ __forceinline__ void gl_lds16(const half8* g, half8* l) {
    __builtin_amdgcn_global_load_lds((const __attribute__((address_space(1))) void*)g,
                                     (__attribute__((address_space(3))) void*)l, 16, 0, 0);
}

// ---------------- Main: 32x32x16 MFMA, A via LDS (BK=128), B depth-2 -------
// Block 128f x 256cols (8b x 32n), 4 waves, wave tile 128x64 = 4(m)x2(n)
// 32x32 tiles -> acc 4x2x16 = 128 AGPR. BK=128 macro double-buffered (64 KB).
// B register-direct, prefetch depth 2 K32 steps via WAR-recycled buffers:
// consume bf[p], then refill the SAME regs with B(dcg+2) -> ~590 cyc cover
// of L2 latency with zero extra VGPRs.
__global__ __launch_bounds__(256, 2) void conv_main(const _Float16* __restrict__ At,
                                                    const _Float16* __restrict__ XB,
                                                    const float* __restrict__ bias,
                                                    const float* __restrict__ dw,
                                                    float* __restrict__ out) {
    __shared__ half8 Abuf[2][8][4][64];   // 64 KB: [buf][kc16][ft][lane]

    int bx    = blockIdx.x;               // 1536 blocks
    int slot  = bx & 7;                   // XCD pin: f_blk per XCD pair
    int f_blk = slot >> 1;                // [0,4)
    int n_blk = 383 - ((bx >> 3) * 2 + (slot & 1));   // largest K first
    int n0 = n_blk << 5;
    int S  = n_blk + 1;                   // true K32 sub-steps
    int M  = (S + 3) >> 2;                // BK=128 macro steps (4 K32 subs each)

    int tid  = threadIdx.x;
    int lane = tid & 63;
    int wid  = tid >> 6;
    int kh   = lane >> 5;                 // k-half within fragment
    int bb   = lane & 7;
    int nh   = (lane >> 3) & 3;

    // A staging: wave wid stages ft-tile wid (32 f rows); 1KB contiguous/load.
    const half8* Ag = (const half8*)At;
    const half8* ag = Ag + ((size_t)(f_blk * 4 + wid) * 768) * 64 + lane;

    // B pointers per n-tile (half8 units). Per-K32 advance = 4*128 = 512.
    const half8* Bg = (const half8*)XB;
    const half8* pB[2];
#pragma unroll
    for (int ti = 0; ti < 2; ++ti) {
        int n_base = n0 + (wid * 2 + ti) * 4;
        int Qt = LL - 1 - n_base - nh;
        int s  = Qt & 7;
        int jc0 = Qt >> 3;                // wave-uniform within tile
        pB[ti] = Bg + (size_t)(jc0 + kh) * 128 + s * 8 + bb;
    }

    f32x16 acc[4][2];
#pragma unroll
    for (int mt = 0; mt < 4; ++mt)
#pragma unroll
        for (int ti = 0; ti < 2; ++ti)
#pragma unroll
            for (int r = 0; r < 16; ++r) acc[mt][ti][r] = 0.f;

    // prologue: stage macro 0 -> buf0; fetch B(0) and B(1) (depth 2)
#pragma unroll
    for (int kc = 0; kc < 8; ++kc)
        gl_lds16(ag + (size_t)kc * 64, &Abuf[0][kc][wid][lane]);
    half8 bf[2][2][2];                    // [parity][kc16][ti]
#pragma unroll
    for (int ti = 0; ti < 2; ++ti) {
        bf[0][0][ti] = pB[ti][0];
        bf[0][1][ti] = pB[ti][256];
        bf[1][0][ti] = pB[ti][512];
        bf[1][1][ti] = pB[ti][768];
    }
    __syncthreads();

    for (int mc = 0; mc < M; ++mc) {
        int buf = mc & 1;
        if (mc + 1 < M) {
            size_t oa = (size_t)(mc + 1) * 512;           // 8 kc x 64 chunks
#pragma unroll
            for (int kc = 0; kc < 8; ++kc)
                gl_lds16(ag + oa + (size_t)kc * 64, &Abuf[buf ^ 1][kc][wid][lane]);
        }
#pragma unroll
        for (int d4 = 0; d4 < 4; ++d4) {
            int dcg = mc * 4 + d4;
            int p   = d4 & 1;             // == dcg&1 since mc*4 is even
            half8 a0[4], a1[4];
#pragma unroll
            for (int mt = 0; mt < 4; ++mt) {
                a0[mt] = Abuf[buf][d4 * 2][mt][lane];
                a1[mt] = Abuf[buf][d4 * 2 + 1][mt][lane];
            }
#pragma unroll
            for (int mt = 0; mt < 4; ++mt)
#pragma unroll
                for (int ti = 0; ti < 2; ++ti)
                    acc[mt][ti] = __builtin_amdgcn_mfma_f32_32x32x16_f16(a0[mt], bf[p][0][ti], acc[mt][ti], 0, 0, 0);
#pragma unroll
            for (int mt = 0; mt < 4; ++mt)
#pragma unroll
                for (int ti = 0; ti < 2; ++ti)
                    acc[mt][ti] = __builtin_amdgcn_mfma_f32_32x32x16_f16(a1[mt], bf[p][1][ti], acc[mt][ti], 0, 0, 0);
            // refill the just-consumed buffer with B(dcg+2): depth-2 prefetch
            size_t ob = (size_t)(dcg + 2) * 512;          // pad-safe, jc <= 1558
#pragma unroll
            for (int ti = 0; ti < 2; ++ti) {
                bf[p][0][ti] = pB[ti][ob];
                bf[p][1][ti] = pB[ti][ob + 256];
            }
        }
        __syncthreads();
    }

    // Epilogue: bias + relu + dense over this block's 128 f rows.
    // C/D 32x32 layout: col = lane&31, row = (reg&3) + 8*(reg>>2) + 4*(lane>>5).
    float p[2][4] = {{0.f}};
#pragma unroll
    for (int mt = 0; mt < 4; ++mt) {
#pragma unroll
        for (int reg = 0; reg < 16; ++reg) {
            int row = (reg & 3) + 8 * (reg >> 2) + 4 * kh;
            int f   = f_blk * 128 + mt * 32 + row;
            float bs = bias[f];
            float4 w = *(const float4*)(dw + (size_t)f * 4);
#pragma unroll
            for (int ti = 0; ti < 2; ++ti) {
                float y = fmaxf(acc[mt][ti][reg] + bs, 0.f);
                p[ti][0] += y * w.x; p[ti][1] += y * w.y;
                p[ti][2] += y * w.z; p[ti][3] += y * w.w;
            }
        }
    }
    // combine the two k-halves (rows differ by 4): lane <-> lane^32
#pragma unroll
    for (int ti = 0; ti < 2; ++ti)
#pragma unroll
        for (int c = 0; c < 4; ++c) {
            float v = p[ti][c];
            v += __shfl_xor(v, 32, 64);
            p[ti][c] = v;
        }
    if (kh == 0) {
#pragma unroll
        for (int ti = 0; ti < 2; ++ti) {
            int n = n0 + (wid * 2 + ti) * 4 + nh;
            float* o = out + ((size_t)bb * LL + n) * 4;
#pragma unroll
            for (int c = 0; c < 4; ++c) atomicAdd(o + c, p[ti][c]);
        }
    }
}

extern "C" void kernel_launch(void* const* d_in, const int* in_sizes, int n_in,
                              void* d_out, int out_size, void* d_ws, size_t ws_size,
                              hipStream_t stream) {
    const int*   ex   = (const int*)d_in[0];
    const float* kern = (const float*)d_in[1];
    const float* bias = (const float*)d_in[2];
    const float* dw   = (const float*)d_in[3];
    const float* db   = (const float*)d_in[4];
    float* out = (float*)d_out;

    _Float16* At = (_Float16*)d_ws;                                   // 12.58 MB
    _Float16* XB = (_Float16*)((char*)d_ws + (size_t)FF * LL * 2);    // +3.19 MB

    hipLaunchKernelGGL(build_At, dim3(3072), dim3(256), 0, stream, kern, At);
    hipLaunchKernelGGL(build_XB, dim3(780),  dim3(256), 0, stream, ex, XB);
    hipLaunchKernelGGL(init_out, dim3(1536), dim3(256), 0, stream, db, out);
    hipLaunchKernelGGL(conv_main, dim3(1536), dim3(256), 0, stream, At, XB, bias, dw, out);
}